// Round 1
// baseline (658.226 us; speedup 1.0000x reference)
//
#include <hip/hip_runtime.h>
#include <hip/hip_cooperative_groups.h>

namespace cg = cooperative_groups;

#define D_ 512
#define L_ 256
#define B_ 16
#define T_ 3072
#define MELS_ 80
#define R_ 4096          // B_*L_ unique token rows
#define CS_ 4104         // mel^T column stride (floats)
#define GRID_ 512        // 2 blocks/CU on 256 CUs — co-residency guaranteed

typedef __bf16 bf16x8 __attribute__((ext_vector_type(8)));
typedef float f32x4 __attribute__((ext_vector_type(4)));

__device__ __forceinline__ unsigned f2bf(float f) {
  union { float f; unsigned u; } x; x.f = f;
  return (x.u + 0x7FFFu + ((x.u >> 16) & 1u)) >> 16;   // RNE
}
__device__ __forceinline__ float bf2f(unsigned h) {
  union { unsigned u; float f; } x; x.u = h << 16;
  return x.f;
}

// dst[n][k] = bf16(src[k][n]) ; src is [512][N] f32, dst is [N][512] bf16
// Entry __syncthreads: blocks now reuse smem across virtual-block iterations.
__device__ __forceinline__ void transw_dev(const float* __restrict__ src,
                                           unsigned short* __restrict__ dst,
                                           int N, int local, float* sh) {
  __syncthreads();
  int kt = local & 7, nt = local >> 3;
  int k0 = kt * 64, n0 = nt * 64;
  int tid = threadIdx.x;
  int c = tid & 63, r4 = tid >> 6;
  for (int it = 0; it < 16; ++it) {
    int r = it * 4 + r4;
    int n = n0 + c;
    sh[r * 65 + c] = (n < N) ? src[(k0 + r) * N + n] : 0.f;
  }
  __syncthreads();
  for (int it = 0; it < 16; ++it) {
    int r = it * 4 + r4;
    int n = n0 + r;
    if (n < N) dst[n * D_ + k0 + c] = (unsigned short)f2bf(sh[c * 65 + r]);
  }
}

// cumsum(dur) + searchsorted(right) -> enc-row index per frame (R_ = invalid)
__device__ __forceinline__ void tok_dev(const int* __restrict__ dur,
                                        int* __restrict__ TOK, int b, int* cs) {
  __syncthreads();
  int tid = threadIdx.x;
  cs[tid] = dur[b * L_ + tid];
  for (int off = 1; off < L_; off <<= 1) {
    __syncthreads();
    int v = (tid >= off) ? cs[tid - off] : 0;
    __syncthreads();
    cs[tid] += v;
  }
  __syncthreads();
  for (int t = tid; t < T_; t += 256) {
    int lo = 0, hi = L_;
    while (lo < hi) { int mid = (lo + hi) >> 1; if (cs[mid] <= t) lo = mid + 1; else hi = mid; }
    TOK[b * T_ + t] = (lo < L_) ? (b * L_ + lo) : R_;
  }
}

// ---- C = relu(A @ Bt^T + bias); 64x64 tile, BK=128 (4 barrier-drains) ----
__device__ __forceinline__ void gemm_tile(
    const unsigned short* __restrict__ A, const unsigned short* __restrict__ Bt,
    const float* __restrict__ bias, unsigned short* __restrict__ C,
    int m0, int n0, int mclamp, int mstore, short* lsA, short* lsB) {
  int tid = threadIdx.x;
  int lane = tid & 63, w = tid >> 6;
  int wm = w >> 1, wn = w & 1;
  int col = lane & 15, quad = lane >> 4;
  f32x4 acc[2][2] = {};
  for (int ks = 0; ks < 4; ++ks) {
    int k0 = ks * 128;
    __syncthreads();                                  // LDS reuse guard
    for (int it = 0; it < 4; ++it) {
      int linear = it * 256 + tid;
      int row = linear >> 4, p = linear & 15;
      int seg = (p + row) & 15;                       // additive swizzle
      const unsigned short* ga = A + (size_t)min(m0 + row, mclamp) * D_ + k0 + seg * 8;
      const unsigned short* gb = Bt + (size_t)(n0 + row) * D_ + k0 + seg * 8;
      short* la = lsA + (size_t)(it * 256 + (tid & ~63)) * 8;  // wave-uniform base
      short* lb = lsB + (size_t)(it * 256 + (tid & ~63)) * 8;
      __builtin_amdgcn_global_load_lds((const __attribute__((address_space(1))) void*)ga,
                                       (__attribute__((address_space(3))) void*)la, 16, 0, 0);
      __builtin_amdgcn_global_load_lds((const __attribute__((address_space(1))) void*)gb,
                                       (__attribute__((address_space(3))) void*)lb, 16, 0, 0);
    }
    __syncthreads();                                  // drains vmcnt(0)
    for (int kk = 0; kk < 4; ++kk) {
      int s = kk * 4 + quad;                          // chunk 0..15 within BK
      bf16x8 af[2], bfr[2];
      for (int mt = 0; mt < 2; ++mt) {
        int r = wm * 32 + mt * 16 + col;
        af[mt] = *(const bf16x8*)(lsA + (size_t)r * 128 + ((s - r) & 15) * 8);
      }
      for (int nt = 0; nt < 2; ++nt) {
        int r = wn * 32 + nt * 16 + col;
        bfr[nt] = *(const bf16x8*)(lsB + (size_t)r * 128 + ((s - r) & 15) * 8);
      }
      for (int mt = 0; mt < 2; ++mt)
        for (int nt = 0; nt < 2; ++nt)
          acc[mt][nt] = __builtin_amdgcn_mfma_f32_16x16x32_bf16(af[mt], bfr[nt], acc[mt][nt], 0, 0, 0);
    }
  }
  for (int nt = 0; nt < 2; ++nt) {
    int n = n0 + wn * 32 + nt * 16 + col;
    float bn = bias[n];
    for (int mt = 0; mt < 2; ++mt) {
      int mb = m0 + wm * 32 + mt * 16 + quad * 4;
      for (int i = 0; i < 4; ++i) {
        int m = mb + i;
        if (m < mstore) {
          float v = acc[mt][nt][i] + bn;
          v = v > 0.f ? v : 0.f;
          C[(size_t)m * D_ + n] = (unsigned short)f2bf(v);
        }
      }
    }
  }
}

// ============ single persistent cooperative kernel: 5 phases, 4 grid syncs ============
__global__ __launch_bounds__(256, 2) void fused(
    const int* __restrict__ src, const int* __restrict__ dur,
    const float* __restrict__ emb, const float* __restrict__ pos,
    const float* __restrict__ Wenc, const float* __restrict__ benc,
    const float* __restrict__ Wdur, const float* __restrict__ bdur,
    const float* __restrict__ Wdec, const float* __restrict__ bdec,
    const float* __restrict__ Wgen, const float* __restrict__ bgen,
    unsigned short* __restrict__ X, unsigned short* __restrict__ ENC,
    unsigned short* __restrict__ DEC, unsigned short* __restrict__ WET,
    unsigned short* __restrict__ WDT, unsigned short* __restrict__ WGT,
    int* __restrict__ TOK, float* __restrict__ MELT,
    float* __restrict__ out, float* __restrict__ durout) {
  __shared__ __align__(16) char smem[32768];
  cg::grid_group grid = cg::this_grid();
  const int gsz = (int)gridDim.x;
  const int tid = threadIdx.x;

  // ---- Phase A: X = bf16(emb[src]+pos), W transposes, ENC zero-row, TOK ----
  for (int vb = blockIdx.x; vb < 673; vb += gsz) {
    if (vb < 512) {
      int lane = tid & 63, w = tid >> 6;
      for (int u = 0; u < 2; ++u) {
        int row = vb * 8 + u * 4 + w;
        int s = src[row];
        int l = row & (L_ - 1);
        int d = lane * 8;
        const float4* ep = (const float4*)(emb + (size_t)s * D_ + d);
        const float4* pp = (const float4*)(pos + (size_t)l * D_ + d);
        float4 a0 = ep[0], a1 = ep[1];
        float4 b0 = pp[0], b1 = pp[1];
        uint4 o;
        o.x = f2bf(a0.x + b0.x) | (f2bf(a0.y + b0.y) << 16);
        o.y = f2bf(a0.z + b0.z) | (f2bf(a0.w + b0.w) << 16);
        o.z = f2bf(a1.x + b1.x) | (f2bf(a1.y + b1.y) << 16);
        o.w = f2bf(a1.z + b1.z) | (f2bf(a1.w + b1.w) << 16);
        *(uint4*)(X + (size_t)row * D_ + d) = o;
      }
    } else if (vb < 576) {
      transw_dev(Wenc, WET, 512, vb - 512, (float*)smem);
    } else if (vb == 576) {
      if (tid < 64) {
        uint4 z = {0u, 0u, 0u, 0u};
        *(uint4*)(ENC + (size_t)R_ * D_ + tid * 8) = z;
      }
    } else if (vb < 641) {
      transw_dev(Wdec, WDT, 512, vb - 577, (float*)smem);
    } else if (vb < 657) {
      transw_dev(Wgen, WGT, MELS_, vb - 641, (float*)smem);
    } else {
      tok_dev(dur, TOK, vb - 657, (int*)smem);
    }
  }
  __threadfence();
  grid.sync();
  __threadfence();

  // ---- Phase B: encoder GEMM (512 tiles, 1/block) ----
  for (int vb = blockIdx.x; vb < 512; vb += gsz)
    gemm_tile(X, WET, benc, ENC, (vb >> 3) * 64, (vb & 7) * 64, R_ - 1, R_,
              (short*)smem, (short*)(smem + 16384));
  __threadfence();
  grid.sync();
  __threadfence();

  // ---- Phase C: decoder GEMM (520 tiles) + duration head (256 vblocks) ----
  for (int vb = blockIdx.x; vb < 776; vb += gsz) {
    if (vb < 520) {
      gemm_tile(ENC, WDT, bdec, DEC, (vb >> 3) * 64, (vb & 7) * 64, R_, R_ + 1,
                (short*)smem, (short*)(smem + 16384));
    } else {
      int lane = tid & 63, w = tid >> 6;
      int b2 = vb - 520;
      float4 w0 = *(const float4*)(Wdur + lane * 8);
      float4 w1 = *(const float4*)(Wdur + lane * 8 + 4);
      float bv = bdur[0];
      for (int rep = 0; rep < 4; ++rep) {
        int row = b2 * 16 + w * 4 + rep;
        const uint4 e = *(const uint4*)(ENC + (size_t)row * D_ + lane * 8);
        float s = 0.f;
        s += bf2f(e.x & 0xffffu) * w0.x;  s += bf2f(e.x >> 16) * w0.y;
        s += bf2f(e.y & 0xffffu) * w0.z;  s += bf2f(e.y >> 16) * w0.w;
        s += bf2f(e.z & 0xffffu) * w1.x;  s += bf2f(e.z >> 16) * w1.y;
        s += bf2f(e.w & 0xffffu) * w1.z;  s += bf2f(e.w >> 16) * w1.w;
        for (int off = 32; off > 0; off >>= 1) s += __shfl_down(s, off, 64);
        if (lane == 0) durout[row] = s + bv;
      }
    }
  }
  __threadfence();
  grid.sync();
  __threadfence();

  // ---- Phase D: mel^T[m][r] = dec[r]·W_gen[:,m] + b_gen[m]; K split over 4 waves ----
  for (int vb = blockIdx.x; vb < 257; vb += gsz) {
    __syncthreads();
    float* sh = (float*)smem;
    int lane = tid & 63, w = tid >> 6;
    int col = lane & 15, quad = lane >> 4;
    int n0 = vb * 16;
    int n = n0 + col;
    int nc = min(n, R_);
    f32x4 acc[5] = {};
    const unsigned short* dp = DEC + (size_t)nc * D_ + quad * 8;
    for (int ks = 0; ks < 4; ++ks) {
      int k0 = (w * 4 + ks) * 32;
      bf16x8 bfr = *(const bf16x8*)(dp + k0);
      for (int mt = 0; mt < 5; ++mt) {
        bf16x8 afr = *(const bf16x8*)(WGT + (size_t)(mt * 16 + col) * D_ + k0 + quad * 8);
        acc[mt] = __builtin_amdgcn_mfma_f32_16x16x32_bf16(afr, bfr, acc[mt], 0, 0, 0);
      }
    }
    for (int mt = 0; mt < 5; ++mt)
      for (int i = 0; i < 4; ++i)
        sh[w * 1280 + (mt * 16 + quad * 4 + i) * 16 + col] = acc[mt][i];
    __syncthreads();
    for (int j = 0; j < 5; ++j) {
      int idx = j * 256 + tid;
      float v = sh[idx] + sh[1280 + idx] + sh[2560 + idx] + sh[3840 + idx];
      int m = idx >> 4;
      int nn = n0 + (idx & 15);
      if (nn <= R_) MELT[(size_t)m * CS_ + nn] = v + bgen[m];
    }
  }
  __threadfence();
  grid.sync();
  __threadfence();

  // ---- Phase E: out[b][m][t] = mel^T[m][tok[b][t]]; float4 coalesced stores ----
  for (int vb = blockIdx.x; vb < 384; vb += gsz) {
    int b = vb & 15, xt = vb >> 4;
    int tl = xt * 128 + (tid & 31) * 4;
    int m0 = tid >> 5;
    int4 tg = *(const int4*)(TOK + b * T_ + tl);
    float* ob = out + (size_t)b * MELS_ * T_ + tl;
    for (int it = 0; it < 10; ++it) {
      int m = m0 + it * 8;
      const float* mr = MELT + (size_t)m * CS_;
      float4 v = make_float4(mr[tg.x], mr[tg.y], mr[tg.z], mr[tg.w]);
      *(float4*)(ob + (size_t)m * T_) = v;
    }
  }
}

extern "C" void kernel_launch(void* const* d_in, const int* in_sizes, int n_in,
                              void* d_out, int out_size, void* d_ws, size_t ws_size,
                              hipStream_t stream) {
  const int* src = (const int*)d_in[0];
  const int* dur = (const int*)d_in[1];
  const float* emb = (const float*)d_in[3];
  const float* pos = (const float*)d_in[4];
  const float* Wenc = (const float*)d_in[5];
  const float* benc = (const float*)d_in[6];
  const float* Wdur = (const float*)d_in[7];
  const float* bdur = (const float*)d_in[8];
  const float* Wdec = (const float*)d_in[9];
  const float* bdec = (const float*)d_in[10];
  const float* Wgen = (const float*)d_in[11];
  const float* bgen = (const float*)d_in[12];

  char* ws = (char*)d_ws;
  unsigned short* X   = (unsigned short*)(ws + 0);          // 4096x512 bf16
  unsigned short* ENC = (unsigned short*)(ws + 4194304);    // 4097x512 bf16 (row 4096 = 0)
  unsigned short* DEC = (unsigned short*)(ws + 8389632);    // 4097x512 bf16
  unsigned short* WET = (unsigned short*)(ws + 12584960);   // W_enc^T 512x512 bf16
  unsigned short* WDT = (unsigned short*)(ws + 13109248);   // W_dec^T 512x512 bf16
  unsigned short* WGT = (unsigned short*)(ws + 13633536);   // W_gen^T 80x512 bf16
  int* TOK            = (int*)(ws + 13715456);              // 16x3072 int
  float* MELT         = (float*)(ws + 13912064);            // 80x4104 f32

  float* out = (float*)d_out;
  float* durout = out + (size_t)B_ * MELS_ * T_;            // 3,932,160

  void* args[] = { &src, &dur, &emb, &pos, &Wenc, &benc, &Wdur, &bdur,
                   &Wdec, &bdec, &Wgen, &bgen,
                   &X, &ENC, &DEC, &WET, &WDT, &WGT, &TOK, &MELT, &out, &durout };
  hipLaunchCooperativeKernel((void*)fused, dim3(GRID_), dim3(256), args, 0, stream);
}

// Round 2
// 368.222 us; speedup vs baseline: 1.7876x; 1.7876x over previous
//
#include <hip/hip_runtime.h>

#define D_ 512
#define L_ 256
#define B_ 16
#define T_ 3072
#define MELS_ 80
#define R_ 4096          // B_*L_ unique token rows
#define CS_ 4104         // mel^T column stride (floats)
#define GRID_ 512        // 2 blocks/CU on 256 CUs — co-residency guaranteed
#define BAR_OFF 15728640 // barrier counters: 15 MiB into ws (past MELT end)

typedef __bf16 bf16x8 __attribute__((ext_vector_type(8)));
typedef float f32x4 __attribute__((ext_vector_type(4)));

__device__ __forceinline__ unsigned f2bf(float f) {
  union { float f; unsigned u; } x; x.f = f;
  return (x.u + 0x7FFFu + ((x.u >> 16) & 1u)) >> 16;   // RNE
}
__device__ __forceinline__ float bf2f(unsigned h) {
  union { unsigned u; float f; } x; x.u = h << 16;
  return x.f;
}

// Hand-rolled grid barrier. Counter per barrier (no reset), zeroed by host memset.
// tid0 only: release fence (1 wbL2/block), relaxed agent atomicAdd, relaxed agent
// spin (no cache-op per poll — atomic agent load is performed at coherence point),
// acquire fence (1 inv/block) once full count observed.
__device__ __forceinline__ void gridbar(unsigned* __restrict__ ctr) {
  __syncthreads();                       // drains vmcnt(0): block's writes are in L2
  if (threadIdx.x == 0) {
    __threadfence();                     // release: flush this XCD's L2 to coherence point
    __hip_atomic_fetch_add(ctr, 1u, __ATOMIC_RELAXED, __HIP_MEMORY_SCOPE_AGENT);
    while (__hip_atomic_load(ctr, __ATOMIC_RELAXED, __HIP_MEMORY_SCOPE_AGENT) < GRID_)
      __builtin_amdgcn_s_sleep(2);
    __threadfence();                     // acquire: invalidate stale L2 lines
  }
  __syncthreads();
}

// dst[n][k] = bf16(src[k][n]) ; src is [512][N] f32, dst is [N][512] bf16
__device__ __forceinline__ void transw_dev(const float* __restrict__ src,
                                           unsigned short* __restrict__ dst,
                                           int N, int local, float* sh) {
  __syncthreads();
  int kt = local & 7, nt = local >> 3;
  int k0 = kt * 64, n0 = nt * 64;
  int tid = threadIdx.x;
  int c = tid & 63, r4 = tid >> 6;
  for (int it = 0; it < 16; ++it) {
    int r = it * 4 + r4;
    int n = n0 + c;
    sh[r * 65 + c] = (n < N) ? src[(k0 + r) * N + n] : 0.f;
  }
  __syncthreads();
  for (int it = 0; it < 16; ++it) {
    int r = it * 4 + r4;
    int n = n0 + r;
    if (n < N) dst[n * D_ + k0 + c] = (unsigned short)f2bf(sh[c * 65 + r]);
  }
}

// cumsum(dur) + searchsorted(right) -> enc-row index per frame (R_ = invalid)
__device__ __forceinline__ void tok_dev(const int* __restrict__ dur,
                                        int* __restrict__ TOK, int b, int* cs) {
  __syncthreads();
  int tid = threadIdx.x;
  cs[tid] = dur[b * L_ + tid];
  for (int off = 1; off < L_; off <<= 1) {
    __syncthreads();
    int v = (tid >= off) ? cs[tid - off] : 0;
    __syncthreads();
    cs[tid] += v;
  }
  __syncthreads();
  for (int t = tid; t < T_; t += 256) {
    int lo = 0, hi = L_;
    while (lo < hi) { int mid = (lo + hi) >> 1; if (cs[mid] <= t) lo = mid + 1; else hi = mid; }
    TOK[b * T_ + t] = (lo < L_) ? (b * L_ + lo) : R_;
  }
}

// ---- C = relu(A @ Bt^T + bias); 64x64 tile, BK=128 (4 barrier-drains) ----
__device__ __forceinline__ void gemm_tile(
    const unsigned short* __restrict__ A, const unsigned short* __restrict__ Bt,
    const float* __restrict__ bias, unsigned short* __restrict__ C,
    int m0, int n0, int mclamp, int mstore, short* lsA, short* lsB) {
  int tid = threadIdx.x;
  int lane = tid & 63, w = tid >> 6;
  int wm = w >> 1, wn = w & 1;
  int col = lane & 15, quad = lane >> 4;
  f32x4 acc[2][2] = {};
  for (int ks = 0; ks < 4; ++ks) {
    int k0 = ks * 128;
    __syncthreads();                                  // LDS reuse guard
    for (int it = 0; it < 4; ++it) {
      int linear = it * 256 + tid;
      int row = linear >> 4, p = linear & 15;
      int seg = (p + row) & 15;                       // additive swizzle
      const unsigned short* ga = A + (size_t)min(m0 + row, mclamp) * D_ + k0 + seg * 8;
      const unsigned short* gb = Bt + (size_t)(n0 + row) * D_ + k0 + seg * 8;
      short* la = lsA + (size_t)(it * 256 + (tid & ~63)) * 8;  // wave-uniform base
      short* lb = lsB + (size_t)(it * 256 + (tid & ~63)) * 8;
      __builtin_amdgcn_global_load_lds((const __attribute__((address_space(1))) void*)ga,
                                       (__attribute__((address_space(3))) void*)la, 16, 0, 0);
      __builtin_amdgcn_global_load_lds((const __attribute__((address_space(1))) void*)gb,
                                       (__attribute__((address_space(3))) void*)lb, 16, 0, 0);
    }
    __syncthreads();                                  // drains vmcnt(0)
    for (int kk = 0; kk < 4; ++kk) {
      int s = kk * 4 + quad;                          // chunk 0..15 within BK
      bf16x8 af[2], bfr[2];
      for (int mt = 0; mt < 2; ++mt) {
        int r = wm * 32 + mt * 16 + col;
        af[mt] = *(const bf16x8*)(lsA + (size_t)r * 128 + ((s - r) & 15) * 8);
      }
      for (int nt = 0; nt < 2; ++nt) {
        int r = wn * 32 + nt * 16 + col;
        bfr[nt] = *(const bf16x8*)(lsB + (size_t)r * 128 + ((s - r) & 15) * 8);
      }
      for (int mt = 0; mt < 2; ++mt)
        for (int nt = 0; nt < 2; ++nt)
          acc[mt][nt] = __builtin_amdgcn_mfma_f32_16x16x32_bf16(af[mt], bfr[nt], acc[mt][nt], 0, 0, 0);
    }
  }
  for (int nt = 0; nt < 2; ++nt) {
    int n = n0 + wn * 32 + nt * 16 + col;
    float bn = bias[n];
    for (int mt = 0; mt < 2; ++mt) {
      int mb = m0 + wm * 32 + mt * 16 + quad * 4;
      for (int i = 0; i < 4; ++i) {
        int m = mb + i;
        if (m < mstore) {
          float v = acc[mt][nt][i] + bn;
          v = v > 0.f ? v : 0.f;
          C[(size_t)m * D_ + n] = (unsigned short)f2bf(v);
        }
      }
    }
  }
}

// ============ single persistent kernel: 5 phases, 4 hand-rolled grid barriers ============
__global__ __launch_bounds__(256, 2) void fused(
    const int* __restrict__ src, const int* __restrict__ dur,
    const float* __restrict__ emb, const float* __restrict__ pos,
    const float* __restrict__ Wenc, const float* __restrict__ benc,
    const float* __restrict__ Wdur, const float* __restrict__ bdur,
    const float* __restrict__ Wdec, const float* __restrict__ bdec,
    const float* __restrict__ Wgen, const float* __restrict__ bgen,
    unsigned short* __restrict__ X, unsigned short* __restrict__ ENC,
    unsigned short* __restrict__ DEC, unsigned short* __restrict__ WET,
    unsigned short* __restrict__ WDT, unsigned short* __restrict__ WGT,
    int* __restrict__ TOK, float* __restrict__ MELT,
    float* __restrict__ out, float* __restrict__ durout,
    unsigned* __restrict__ BAR) {
  __shared__ __align__(16) char smem[32768];
  const int gsz = (int)gridDim.x;
  const int tid = threadIdx.x;

  // ---- Phase A: X = bf16(emb[src]+pos), W transposes, ENC zero-row, TOK ----
  for (int vb = blockIdx.x; vb < 673; vb += gsz) {
    if (vb < 512) {
      int lane = tid & 63, w = tid >> 6;
      for (int u = 0; u < 2; ++u) {
        int row = vb * 8 + u * 4 + w;
        int s = src[row];
        int l = row & (L_ - 1);
        int d = lane * 8;
        const float4* ep = (const float4*)(emb + (size_t)s * D_ + d);
        const float4* pp = (const float4*)(pos + (size_t)l * D_ + d);
        float4 a0 = ep[0], a1 = ep[1];
        float4 b0 = pp[0], b1 = pp[1];
        uint4 o;
        o.x = f2bf(a0.x + b0.x) | (f2bf(a0.y + b0.y) << 16);
        o.y = f2bf(a0.z + b0.z) | (f2bf(a0.w + b0.w) << 16);
        o.z = f2bf(a1.x + b1.x) | (f2bf(a1.y + b1.y) << 16);
        o.w = f2bf(a1.z + b1.z) | (f2bf(a1.w + b1.w) << 16);
        *(uint4*)(X + (size_t)row * D_ + d) = o;
      }
    } else if (vb < 576) {
      transw_dev(Wenc, WET, 512, vb - 512, (float*)smem);
    } else if (vb == 576) {
      if (tid < 64) {
        uint4 z = {0u, 0u, 0u, 0u};
        *(uint4*)(ENC + (size_t)R_ * D_ + tid * 8) = z;
      }
    } else if (vb < 641) {
      transw_dev(Wdec, WDT, 512, vb - 577, (float*)smem);
    } else if (vb < 657) {
      transw_dev(Wgen, WGT, MELS_, vb - 641, (float*)smem);
    } else {
      tok_dev(dur, TOK, vb - 657, (int*)smem);
    }
  }
  gridbar(BAR + 0 * 32);

  // ---- Phase B: encoder GEMM (512 tiles, 1/block) ----
  for (int vb = blockIdx.x; vb < 512; vb += gsz)
    gemm_tile(X, WET, benc, ENC, (vb >> 3) * 64, (vb & 7) * 64, R_ - 1, R_,
              (short*)smem, (short*)(smem + 16384));
  gridbar(BAR + 1 * 32);

  // ---- Phase C: decoder GEMM (520 tiles) + duration head (256 vblocks) ----
  for (int vb = blockIdx.x; vb < 776; vb += gsz) {
    if (vb < 520) {
      gemm_tile(ENC, WDT, bdec, DEC, (vb >> 3) * 64, (vb & 7) * 64, R_, R_ + 1,
                (short*)smem, (short*)(smem + 16384));
    } else {
      int lane = tid & 63, w = tid >> 6;
      int b2 = vb - 520;
      float4 w0 = *(const float4*)(Wdur + lane * 8);
      float4 w1 = *(const float4*)(Wdur + lane * 8 + 4);
      float bv = bdur[0];
      for (int rep = 0; rep < 4; ++rep) {
        int row = b2 * 16 + w * 4 + rep;
        const uint4 e = *(const uint4*)(ENC + (size_t)row * D_ + lane * 8);
        float s = 0.f;
        s += bf2f(e.x & 0xffffu) * w0.x;  s += bf2f(e.x >> 16) * w0.y;
        s += bf2f(e.y & 0xffffu) * w0.z;  s += bf2f(e.y >> 16) * w0.w;
        s += bf2f(e.z & 0xffffu) * w1.x;  s += bf2f(e.z >> 16) * w1.y;
        s += bf2f(e.w & 0xffffu) * w1.z;  s += bf2f(e.w >> 16) * w1.w;
        for (int off = 32; off > 0; off >>= 1) s += __shfl_down(s, off, 64);
        if (lane == 0) durout[row] = s + bv;
      }
    }
  }
  gridbar(BAR + 2 * 32);

  // ---- Phase D: mel^T[m][r] = dec[r]·W_gen[:,m] + b_gen[m]; K split over 4 waves ----
  for (int vb = blockIdx.x; vb < 257; vb += gsz) {
    __syncthreads();
    float* sh = (float*)smem;
    int lane = tid & 63, w = tid >> 6;
    int col = lane & 15, quad = lane >> 4;
    int n0 = vb * 16;
    int n = n0 + col;
    int nc = min(n, R_);
    f32x4 acc[5] = {};
    const unsigned short* dp = DEC + (size_t)nc * D_ + quad * 8;
    for (int ks = 0; ks < 4; ++ks) {
      int k0 = (w * 4 + ks) * 32;
      bf16x8 bfr = *(const bf16x8*)(dp + k0);
      for (int mt = 0; mt < 5; ++mt) {
        bf16x8 afr = *(const bf16x8*)(WGT + (size_t)(mt * 16 + col) * D_ + k0 + quad * 8);
        acc[mt] = __builtin_amdgcn_mfma_f32_16x16x32_bf16(afr, bfr, acc[mt], 0, 0, 0);
      }
    }
    for (int mt = 0; mt < 5; ++mt)
      for (int i = 0; i < 4; ++i)
        sh[w * 1280 + (mt * 16 + quad * 4 + i) * 16 + col] = acc[mt][i];
    __syncthreads();
    for (int j = 0; j < 5; ++j) {
      int idx = j * 256 + tid;
      float v = sh[idx] + sh[1280 + idx] + sh[2560 + idx] + sh[3840 + idx];
      int m = idx >> 4;
      int nn = n0 + (idx & 15);
      if (nn <= R_) MELT[(size_t)m * CS_ + nn] = v + bgen[m];
    }
  }
  gridbar(BAR + 3 * 32);

  // ---- Phase E: out[b][m][t] = mel^T[m][tok[b][t]]; float4 coalesced stores ----
  for (int vb = blockIdx.x; vb < 384; vb += gsz) {
    int b = vb & 15, xt = vb >> 4;
    int tl = xt * 128 + (tid & 31) * 4;
    int m0 = tid >> 5;
    int4 tg = *(const int4*)(TOK + b * T_ + tl);
    float* ob = out + (size_t)b * MELS_ * T_ + tl;
    for (int it = 0; it < 10; ++it) {
      int m = m0 + it * 8;
      const float* mr = MELT + (size_t)m * CS_;
      float4 v = make_float4(mr[tg.x], mr[tg.y], mr[tg.z], mr[tg.w]);
      *(float4*)(ob + (size_t)m * T_) = v;
    }
  }
}

extern "C" void kernel_launch(void* const* d_in, const int* in_sizes, int n_in,
                              void* d_out, int out_size, void* d_ws, size_t ws_size,
                              hipStream_t stream) {
  const int* src = (const int*)d_in[0];
  const int* dur = (const int*)d_in[1];
  const float* emb = (const float*)d_in[3];
  const float* pos = (const float*)d_in[4];
  const float* Wenc = (const float*)d_in[5];
  const float* benc = (const float*)d_in[6];
  const float* Wdur = (const float*)d_in[7];
  const float* bdur = (const float*)d_in[8];
  const float* Wdec = (const float*)d_in[9];
  const float* bdec = (const float*)d_in[10];
  const float* Wgen = (const float*)d_in[11];
  const float* bgen = (const float*)d_in[12];

  char* ws = (char*)d_ws;
  unsigned short* X   = (unsigned short*)(ws + 0);          // 4096x512 bf16
  unsigned short* ENC = (unsigned short*)(ws + 4194304);    // 4097x512 bf16 (row 4096 = 0)
  unsigned short* DEC = (unsigned short*)(ws + 8389632);    // 4097x512 bf16
  unsigned short* WET = (unsigned short*)(ws + 12584960);   // W_enc^T 512x512 bf16
  unsigned short* WDT = (unsigned short*)(ws + 13109248);   // W_dec^T 512x512 bf16
  unsigned short* WGT = (unsigned short*)(ws + 13633536);   // W_gen^T 80x512 bf16
  int* TOK            = (int*)(ws + 13715456);              // 16x3072 int
  float* MELT         = (float*)(ws + 13912064);            // 80x4104 f32
  unsigned* BAR       = (unsigned*)(ws + BAR_OFF);          // 4 barrier counters (128B apart)

  float* out = (float*)d_out;
  float* durout = out + (size_t)B_ * MELS_ * T_;            // 3,932,160

  // zero the barrier counters (workspace is poisoned before each iteration)
  hipMemsetAsync(BAR, 0, 4 * 32 * sizeof(unsigned), stream);

  void* args[] = { &src, &dur, &emb, &pos, &Wenc, &benc, &Wdur, &bdur,
                   &Wdec, &bdec, &Wgen, &bgen,
                   &X, &ENC, &DEC, &WET, &WDT, &WGT, &TOK, &MELT, &out, &durout, &BAR };
  hipLaunchCooperativeKernel((void*)fused, dim3(GRID_), dim3(256), args, 0, stream);
}

// Round 3
// 140.180 us; speedup vs baseline: 4.6956x; 2.6268x over previous
//
#include <hip/hip_runtime.h>

#define D_ 512
#define L_ 256
#define B_ 16
#define T_ 3072
#define MELS_ 80
#define R_ 4096          // B_*L_ unique token rows
#define CS_ 4104         // mel^T column stride (floats)

typedef __bf16 bf16x8 __attribute__((ext_vector_type(8)));
typedef float f32x4 __attribute__((ext_vector_type(4)));

__device__ __forceinline__ unsigned f2bf(float f) {
  union { float f; unsigned u; } x; x.f = f;
  return (x.u + 0x7FFFu + ((x.u >> 16) & 1u)) >> 16;   // RNE
}
__device__ __forceinline__ float bf2f(unsigned h) {
  union { unsigned u; float f; } x; x.u = h << 16;
  return x.f;
}

// dst[n][k] = bf16(src[k][n]) ; src is [512][N] f32, dst is [N][512] bf16
__device__ __forceinline__ void transw_dev(const float* __restrict__ src,
                                           unsigned short* __restrict__ dst,
                                           int N, int local, float* sh) {
  int kt = local & 7, nt = local >> 3;
  int k0 = kt * 64, n0 = nt * 64;
  int tid = threadIdx.x;
  int c = tid & 63, r4 = tid >> 6;
  for (int it = 0; it < 16; ++it) {
    int r = it * 4 + r4;
    int n = n0 + c;
    sh[r * 65 + c] = (n < N) ? src[(k0 + r) * N + n] : 0.f;
  }
  __syncthreads();
  for (int it = 0; it < 16; ++it) {
    int r = it * 4 + r4;
    int n = n0 + r;
    if (n < N) dst[n * D_ + k0 + c] = (unsigned short)f2bf(sh[c * 65 + r]);
  }
}

// cumsum(dur) + searchsorted(right) -> enc-row index per frame (R_ = invalid)
__device__ __forceinline__ void tok_dev(const int* __restrict__ dur,
                                        int* __restrict__ TOK, int b, int* cs) {
  int tid = threadIdx.x;
  cs[tid] = dur[b * L_ + tid];
  for (int off = 1; off < L_; off <<= 1) {
    __syncthreads();
    int v = (tid >= off) ? cs[tid - off] : 0;
    __syncthreads();
    cs[tid] += v;
  }
  __syncthreads();
  for (int t = tid; t < T_; t += 256) {
    int lo = 0, hi = L_;
    while (lo < hi) { int mid = (lo + hi) >> 1; if (cs[mid] <= t) lo = mid + 1; else hi = mid; }
    TOK[b * T_ + t] = (lo < L_) ? (b * L_ + lo) : R_;
  }
}

// ---- C = relu(A @ Bt^T + bias); 64x64 tile, BK=128; A from precomputed buffer ----
__device__ __forceinline__ void gemm_tile(
    const unsigned short* __restrict__ A, const unsigned short* __restrict__ Bt,
    const float* __restrict__ bias, unsigned short* __restrict__ C,
    int m0, int n0, int mclamp, int mstore, short* lsA, short* lsB) {
  int tid = threadIdx.x;
  int lane = tid & 63, w = tid >> 6;
  int wm = w >> 1, wn = w & 1;
  int col = lane & 15, quad = lane >> 4;
  f32x4 acc[2][2] = {};
  for (int ks = 0; ks < 4; ++ks) {
    int k0 = ks * 128;
    __syncthreads();                                  // LDS reuse guard
    for (int it = 0; it < 4; ++it) {
      int linear = it * 256 + tid;
      int row = linear >> 4, p = linear & 15;
      int seg = (p + row) & 15;                       // additive swizzle
      const unsigned short* ga = A + (size_t)min(m0 + row, mclamp) * D_ + k0 + seg * 8;
      const unsigned short* gb = Bt + (size_t)(n0 + row) * D_ + k0 + seg * 8;
      short* la = lsA + (size_t)(it * 256 + (tid & ~63)) * 8;  // wave-uniform base
      short* lb = lsB + (size_t)(it * 256 + (tid & ~63)) * 8;
      __builtin_amdgcn_global_load_lds((const __attribute__((address_space(1))) void*)ga,
                                       (__attribute__((address_space(3))) void*)la, 16, 0, 0);
      __builtin_amdgcn_global_load_lds((const __attribute__((address_space(1))) void*)gb,
                                       (__attribute__((address_space(3))) void*)lb, 16, 0, 0);
    }
    __syncthreads();                                  // drains vmcnt(0)
    for (int kk = 0; kk < 4; ++kk) {
      int s = kk * 4 + quad;                          // chunk 0..15 within BK
      bf16x8 af[2], bfr[2];
      for (int mt = 0; mt < 2; ++mt) {
        int r = wm * 32 + mt * 16 + col;
        af[mt] = *(const bf16x8*)(lsA + (size_t)r * 128 + ((s - r) & 15) * 8);
      }
      for (int nt = 0; nt < 2; ++nt) {
        int r = wn * 32 + nt * 16 + col;
        bfr[nt] = *(const bf16x8*)(lsB + (size_t)r * 128 + ((s - r) & 15) * 8);
      }
      for (int mt = 0; mt < 2; ++mt)
        for (int nt = 0; nt < 2; ++nt)
          acc[mt][nt] = __builtin_amdgcn_mfma_f32_16x16x32_bf16(af[mt], bfr[nt], acc[mt][nt], 0, 0, 0);
    }
  }
  for (int nt = 0; nt < 2; ++nt) {
    int n = n0 + wn * 32 + nt * 16 + col;
    float bn = bias[n];
    for (int mt = 0; mt < 2; ++mt) {
      int mb = m0 + wm * 32 + mt * 16 + quad * 4;
      for (int i = 0; i < 4; ++i) {
        int m = mb + i;
        if (m < mstore) {
          float v = acc[mt][nt][i] + bn;
          v = v > 0.f ? v : 0.f;
          C[(size_t)m * D_ + n] = (unsigned short)f2bf(v);
        }
      }
    }
  }
}

// ---- K1: WET transpose (64 blks) + ENC zero-row (1 blk) ----
__global__ void prep1(const float* __restrict__ Wenc, unsigned short* __restrict__ WET,
                      unsigned short* __restrict__ ENC) {
  __shared__ float sh[64 * 65];
  int bid = blockIdx.x, tid = threadIdx.x;
  if (bid < 64) {
    transw_dev(Wenc, WET, 512, bid, sh);
  } else {
    if (tid < 64) {
      uint4 z = {0u, 0u, 0u, 0u};
      *(uint4*)(ENC + (size_t)R_ * D_ + tid * 8) = z;
    }
  }
}

// ---- K2: encoder GEMM with inline emb[src]+pos A-gather (512 blks) + prep tails ----
__global__ __launch_bounds__(256, 4) void gemm_enc(
    const int* __restrict__ src, const float* __restrict__ emb,
    const float* __restrict__ pos, const unsigned short* __restrict__ WET,
    const float* __restrict__ benc, unsigned short* __restrict__ ENC,
    const float* __restrict__ Wdec, const float* __restrict__ Wgen,
    const int* __restrict__ dur,
    unsigned short* __restrict__ WDT, unsigned short* __restrict__ WGT,
    int* __restrict__ TOK) {
  __shared__ __align__(16) char smem[32768];
  int bid = blockIdx.x;
  if (bid >= 512) {
    if (bid < 576)      transw_dev(Wdec, WDT, 512, bid - 512, (float*)smem);
    else if (bid < 592) transw_dev(Wgen, WGT, MELS_, bid - 576, (float*)smem);
    else                tok_dev(dur, TOK, bid - 592, (int*)smem);
    return;
  }
  short* lsA = (short*)smem;
  short* lsB = (short*)(smem + 16384);
  int m0 = (bid >> 3) * 64, n0 = (bid & 7) * 64;
  int tid = threadIdx.x;
  int lane = tid & 63, w = tid >> 6;
  int wm = w >> 1, wn = w & 1;
  int col = lane & 15, quad = lane >> 4;
  // A-gather mapping: 4 threads per tile-row, 32 cols (4 swizzled 8-chunks) each
  int arow = tid >> 2, cq = tid & 3;
  int am = m0 + arow;                                  // always < R_
  int asrc = src[am];
  const float* ep = emb + (size_t)asrc * D_ + cq * 32;
  const float* pp = pos + (size_t)(am & (L_ - 1)) * D_ + cq * 32;
  f32x4 acc[2][2] = {};
  for (int ks = 0; ks < 4; ++ks) {
    int k0 = ks * 128;
    __syncthreads();                                  // LDS reuse guard
    // B staging via global_load_lds (async, in flight during A gather)
    for (int it = 0; it < 4; ++it) {
      int linear = it * 256 + tid;
      int row = linear >> 4, p = linear & 15;
      int seg = (p + row) & 15;
      const unsigned short* gb = WET + (size_t)(n0 + row) * D_ + k0 + seg * 8;
      short* lb = lsB + (size_t)(it * 256 + (tid & ~63)) * 8;
      __builtin_amdgcn_global_load_lds((const __attribute__((address_space(1))) void*)gb,
                                       (__attribute__((address_space(3))) void*)lb, 16, 0, 0);
    }
    // A staging: X-tile computed on the fly (emb+pos -> bf16), swizzled ds_write
    {
      const float4* e4 = (const float4*)(ep + k0);
      const float4* p4 = (const float4*)(pp + k0);
#pragma unroll
      for (int j = 0; j < 4; ++j) {
        float4 a0 = e4[2 * j], a1 = e4[2 * j + 1];
        float4 b0 = p4[2 * j], b1 = p4[2 * j + 1];
        uint4 o;
        o.x = f2bf(a0.x + b0.x) | (f2bf(a0.y + b0.y) << 16);
        o.y = f2bf(a0.z + b0.z) | (f2bf(a0.w + b0.w) << 16);
        o.z = f2bf(a1.x + b1.x) | (f2bf(a1.y + b1.y) << 16);
        o.w = f2bf(a1.z + b1.z) | (f2bf(a1.w + b1.w) << 16);
        int g = cq * 4 + j;                            // global 8-chunk index
        *(uint4*)(lsA + (size_t)arow * 128 + ((g - arow) & 15) * 8) = o;
      }
    }
    __syncthreads();                                  // drains vmcnt + lgkmcnt
    for (int kk = 0; kk < 4; ++kk) {
      int s = kk * 4 + quad;
      bf16x8 af[2], bfr[2];
      for (int mt = 0; mt < 2; ++mt) {
        int r = wm * 32 + mt * 16 + col;
        af[mt] = *(const bf16x8*)(lsA + (size_t)r * 128 + ((s - r) & 15) * 8);
      }
      for (int nt = 0; nt < 2; ++nt) {
        int r = wn * 32 + nt * 16 + col;
        bfr[nt] = *(const bf16x8*)(lsB + (size_t)r * 128 + ((s - r) & 15) * 8);
      }
      for (int mt = 0; mt < 2; ++mt)
        for (int nt = 0; nt < 2; ++nt)
          acc[mt][nt] = __builtin_amdgcn_mfma_f32_16x16x32_bf16(af[mt], bfr[nt], acc[mt][nt], 0, 0, 0);
    }
  }
  for (int nt = 0; nt < 2; ++nt) {
    int n = n0 + wn * 32 + nt * 16 + col;
    float bn = benc[n];
    for (int mt = 0; mt < 2; ++mt) {
      int mb = m0 + wm * 32 + mt * 16 + quad * 4;
      for (int i = 0; i < 4; ++i) {
        float v = acc[mt][nt][i] + bn;
        v = v > 0.f ? v : 0.f;
        ENC[(size_t)(mb + i) * D_ + n] = (unsigned short)f2bf(v);
      }
    }
  }
}

// ---- K3: decoder GEMM (520 blks) + duration head (256 tail blks) ----
__global__ __launch_bounds__(256, 4) void gemm_dec(
    const unsigned short* __restrict__ ENC, const unsigned short* __restrict__ WDT,
    const float* __restrict__ bdec, unsigned short* __restrict__ DEC,
    const float* __restrict__ wdur, const float* __restrict__ bdur,
    float* __restrict__ durout) {
  __shared__ __align__(16) char smem[32768];
  int bid = blockIdx.x, tid = threadIdx.x;
  int lane = tid & 63, w = tid >> 6;
  if (bid >= 520) {                                   // duration head: 16 rows/block
    int b2 = bid - 520;
    float4 w0 = *(const float4*)(wdur + lane * 8);
    float4 w1 = *(const float4*)(wdur + lane * 8 + 4);
    float bv = bdur[0];
    for (int rep = 0; rep < 4; ++rep) {
      int row = b2 * 16 + w * 4 + rep;
      const uint4 e = *(const uint4*)(ENC + (size_t)row * D_ + lane * 8);
      float s = 0.f;
      s += bf2f(e.x & 0xffffu) * w0.x;  s += bf2f(e.x >> 16) * w0.y;
      s += bf2f(e.y & 0xffffu) * w0.z;  s += bf2f(e.y >> 16) * w0.w;
      s += bf2f(e.z & 0xffffu) * w1.x;  s += bf2f(e.z >> 16) * w1.y;
      s += bf2f(e.w & 0xffffu) * w1.z;  s += bf2f(e.w >> 16) * w1.w;
      for (int off = 32; off > 0; off >>= 1) s += __shfl_down(s, off, 64);
      if (lane == 0) durout[row] = s + bv;
    }
    return;
  }
  gemm_tile(ENC, WDT, bdec, DEC, (bid >> 3) * 64, (bid & 7) * 64, R_, R_ + 1,
            (short*)smem, (short*)(smem + 16384));
}

// ---- K4: mel^T[m][r] = dec[r]·W_gen[:,m] + b_gen[m] ; K split over 4 waves ----
__global__ void genk(const unsigned short* __restrict__ dec, const unsigned short* __restrict__ wgT,
                     const float* __restrict__ bgen, float* __restrict__ melT) {
  __shared__ float sh[4 * 80 * 16];
  int tid = threadIdx.x;
  int lane = tid & 63, w = tid >> 6;
  int col = lane & 15, quad = lane >> 4;
  int n0 = blockIdx.x * 16;
  int n = n0 + col;
  int nc = min(n, R_);
  f32x4 acc[5] = {};
  const unsigned short* dp = dec + (size_t)nc * D_ + quad * 8;
  for (int ks = 0; ks < 4; ++ks) {
    int k0 = (w * 4 + ks) * 32;
    bf16x8 bfr = *(const bf16x8*)(dp + k0);
    for (int mt = 0; mt < 5; ++mt) {
      bf16x8 afr = *(const bf16x8*)(wgT + (size_t)(mt * 16 + col) * D_ + k0 + quad * 8);
      acc[mt] = __builtin_amdgcn_mfma_f32_16x16x32_bf16(afr, bfr, acc[mt], 0, 0, 0);
    }
  }
  for (int mt = 0; mt < 5; ++mt)
    for (int i = 0; i < 4; ++i)
      sh[w * 1280 + (mt * 16 + quad * 4 + i) * 16 + col] = acc[mt][i];
  __syncthreads();
  for (int j = 0; j < 5; ++j) {
    int idx = j * 256 + tid;
    float v = sh[idx] + sh[1280 + idx] + sh[2560 + idx] + sh[3840 + idx];
    int m = idx >> 4;
    int nn = n0 + (idx & 15);
    if (nn <= R_) melT[(size_t)m * CS_ + nn] = v + bgen[m];
  }
}

// ---- K5: out[b][m][t] = mel^T[m][tok[b][t]] ; float4 coalesced stores ----
__global__ void outk(const int* __restrict__ TOK, const float* __restrict__ melT,
                     float* __restrict__ out) {
  int b = blockIdx.y;
  int tl = blockIdx.x * 128 + (threadIdx.x & 31) * 4;
  int m0 = threadIdx.x >> 5;
  int4 tg = *(const int4*)(TOK + b * T_ + tl);
  float* ob = out + (size_t)b * MELS_ * T_ + tl;
  for (int it = 0; it < 10; ++it) {
    int m = m0 + it * 8;
    const float* mr = melT + (size_t)m * CS_;
    float4 v = make_float4(mr[tg.x], mr[tg.y], mr[tg.z], mr[tg.w]);
    *(float4*)(ob + (size_t)m * T_) = v;
  }
}

extern "C" void kernel_launch(void* const* d_in, const int* in_sizes, int n_in,
                              void* d_out, int out_size, void* d_ws, size_t ws_size,
                              hipStream_t stream) {
  const int* src = (const int*)d_in[0];
  const int* dur = (const int*)d_in[1];
  const float* emb = (const float*)d_in[3];
  const float* pos = (const float*)d_in[4];
  const float* Wenc = (const float*)d_in[5];
  const float* benc = (const float*)d_in[6];
  const float* Wdur = (const float*)d_in[7];
  const float* bdur = (const float*)d_in[8];
  const float* Wdec = (const float*)d_in[9];
  const float* bdec = (const float*)d_in[10];
  const float* Wgen = (const float*)d_in[11];
  const float* bgen = (const float*)d_in[12];

  char* ws = (char*)d_ws;
  unsigned short* ENC = (unsigned short*)(ws + 4194304);    // 4097x512 bf16 (row 4096 = 0)
  unsigned short* DEC = (unsigned short*)(ws + 8389632);    // 4097x512 bf16
  unsigned short* WET = (unsigned short*)(ws + 12584960);   // W_enc^T 512x512 bf16
  unsigned short* WDT = (unsigned short*)(ws + 13109248);   // W_dec^T 512x512 bf16
  unsigned short* WGT = (unsigned short*)(ws + 13633536);   // W_gen^T 80x512 bf16
  int* TOK            = (int*)(ws + 13715456);              // 16x3072 int
  float* MELT         = (float*)(ws + 13912064);            // 80x4104 f32

  float* out = (float*)d_out;
  float* durout = out + (size_t)B_ * MELS_ * T_;            // 3,932,160

  prep1<<<65, 256, 0, stream>>>(Wenc, WET, ENC);
  gemm_enc<<<608, 256, 0, stream>>>(src, emb, pos, WET, benc, ENC, Wdec, Wgen, dur, WDT, WGT, TOK);
  gemm_dec<<<776, 256, 0, stream>>>(ENC, WDT, bdec, DEC, Wdur, bdur, durout);
  genk<<<257, 256, 0, stream>>>(DEC, WGT, bgen, MELT);
  outk<<<dim3(24, 16), 256, 0, stream>>>(TOK, MELT, out);
}

// Round 5
// 128.657 us; speedup vs baseline: 5.1161x; 1.0896x over previous
//
#include <hip/hip_runtime.h>

#define D_ 512
#define L_ 256
#define B_ 16
#define T_ 3072
#define MELS_ 80
#define R_ 4096          // B_*L_ unique token rows
#define CS_ 4104         // mel^T column stride (floats)

typedef __bf16 bf16x8 __attribute__((ext_vector_type(8)));
typedef float f32x4 __attribute__((ext_vector_type(4)));

__device__ __forceinline__ unsigned f2bf(float f) {
  union { float f; unsigned u; } x; x.f = f;
  return (x.u + 0x7FFFu + ((x.u >> 16) & 1u)) >> 16;   // RNE
}
__device__ __forceinline__ float bf2f(unsigned h) {
  union { unsigned u; float f; } x; x.u = h << 16;
  return x.f;
}

// dst[n][k] = bf16(src[k][n]) ; src is [512][N] f32, dst is [N][512] bf16
__device__ __forceinline__ void transw_dev(const float* __restrict__ src,
                                           unsigned short* __restrict__ dst,
                                           int N, int local, float* sh) {
  int kt = local & 7, nt = local >> 3;
  int k0 = kt * 64, n0 = nt * 64;
  int tid = threadIdx.x;
  int c = tid & 63, r4 = tid >> 6;
  for (int it = 0; it < 16; ++it) {
    int r = it * 4 + r4;
    int n = n0 + c;
    sh[r * 65 + c] = (n < N) ? src[(k0 + r) * N + n] : 0.f;
  }
  __syncthreads();
  for (int it = 0; it < 16; ++it) {
    int r = it * 4 + r4;
    int n = n0 + r;
    if (n < N) dst[n * D_ + k0 + c] = (unsigned short)f2bf(sh[c * 65 + r]);
  }
}

// cumsum(dur) + searchsorted(right) -> enc-row index per frame (R_ = invalid)
__device__ __forceinline__ void tok_dev(const int* __restrict__ dur,
                                        int* __restrict__ TOK, int b, int* cs) {
  int tid = threadIdx.x;
  cs[tid] = dur[b * L_ + tid];
  for (int off = 1; off < L_; off <<= 1) {
    __syncthreads();
    int v = (tid >= off) ? cs[tid - off] : 0;
    __syncthreads();
    cs[tid] += v;
  }
  __syncthreads();
  for (int t = tid; t < T_; t += 256) {
    int lo = 0, hi = L_;
    while (lo < hi) { int mid = (lo + hi) >> 1; if (cs[mid] <= t) lo = mid + 1; else hi = mid; }
    TOK[b * T_ + t] = (lo < L_) ? (b * L_ + lo) : R_;
  }
}

// issue one 64x128 A-tile + one 64x128 B-tile of async global->LDS loads (no wait)
__device__ __forceinline__ void stage_ab(
    const unsigned short* __restrict__ A, const unsigned short* __restrict__ Bt,
    int m0, int n0, int mclamp, int k0, short* lsA, short* lsB, int tid) {
#pragma unroll
  for (int it = 0; it < 4; ++it) {
    int linear = it * 256 + tid;
    int row = linear >> 4, p = linear & 15;
    int seg = (p + row) & 15;                         // additive swizzle
    const unsigned short* ga = A + (size_t)min(m0 + row, mclamp) * D_ + k0 + seg * 8;
    const unsigned short* gb = Bt + (size_t)(n0 + row) * D_ + k0 + seg * 8;
    short* la = lsA + (size_t)(it * 256 + (tid & ~63)) * 8;  // wave-uniform base
    short* lb = lsB + (size_t)(it * 256 + (tid & ~63)) * 8;
    __builtin_amdgcn_global_load_lds((const __attribute__((address_space(1))) void*)ga,
                                     (__attribute__((address_space(3))) void*)la, 16, 0, 0);
    __builtin_amdgcn_global_load_lds((const __attribute__((address_space(1))) void*)gb,
                                     (__attribute__((address_space(3))) void*)lb, 16, 0, 0);
  }
}

// ---- C = relu(A @ Bt^T + bias); 64x64 tile, BK=128, double-buffered LDS ----
// 2-phase pipeline: stage(t+1) in flight during MFMA(t); one barrier per K-step.
__device__ __forceinline__ void gemm_tile(
    const unsigned short* __restrict__ A, const unsigned short* __restrict__ Bt,
    const float* __restrict__ bias, unsigned short* __restrict__ C,
    int m0, int n0, int mclamp, int mstore, char* smem) {
  short* lsA0 = (short*)smem;
  short* lsB0 = (short*)(smem + 16384);
  short* lsA1 = (short*)(smem + 32768);
  short* lsB1 = (short*)(smem + 49152);
  int tid = threadIdx.x;
  int lane = tid & 63, w = tid >> 6;
  int wm = w >> 1, wn = w & 1;
  int col = lane & 15, quad = lane >> 4;
  f32x4 acc[2][2] = {};
  stage_ab(A, Bt, m0, n0, mclamp, 0, lsA0, lsB0, tid);
  __syncthreads();                                    // drains vmcnt(0): buf0 ready
#pragma unroll
  for (int ks = 0; ks < 4; ++ks) {                    // ks compile-time after unroll
    short* cA = (ks & 1) ? lsA1 : lsA0;
    short* cB = (ks & 1) ? lsB1 : lsB0;
    short* nA = (ks & 1) ? lsA0 : lsA1;
    short* nB = (ks & 1) ? lsB0 : lsB1;
    if (ks < 3) stage_ab(A, Bt, m0, n0, mclamp, (ks + 1) * 128, nA, nB, tid);
#pragma unroll
    for (int kk = 0; kk < 4; ++kk) {
      int s = kk * 4 + quad;                          // chunk 0..15 within BK
      bf16x8 af[2], bfr[2];
#pragma unroll
      for (int mt = 0; mt < 2; ++mt) {
        int r = wm * 32 + mt * 16 + col;
        af[mt] = *(const bf16x8*)(cA + (size_t)r * 128 + ((s - r) & 15) * 8);
      }
#pragma unroll
      for (int nt = 0; nt < 2; ++nt) {
        int r = wn * 32 + nt * 16 + col;
        bfr[nt] = *(const bf16x8*)(cB + (size_t)r * 128 + ((s - r) & 15) * 8);
      }
#pragma unroll
      for (int mt = 0; mt < 2; ++mt)
#pragma unroll
        for (int nt = 0; nt < 2; ++nt)
          acc[mt][nt] = __builtin_amdgcn_mfma_f32_16x16x32_bf16(af[mt], bfr[nt], acc[mt][nt], 0, 0, 0);
    }
    if (ks < 3) __syncthreads();                      // next buf ready + cur buf safe to overwrite
  }
  for (int nt = 0; nt < 2; ++nt) {
    int n = n0 + wn * 32 + nt * 16 + col;
    float bn = bias[n];
    for (int mt = 0; mt < 2; ++mt) {
      int mb = m0 + wm * 32 + mt * 16 + quad * 4;
      for (int i = 0; i < 4; ++i) {
        int m = mb + i;
        if (m < mstore) {
          float v = acc[mt][nt][i] + bn;
          v = v > 0.f ? v : 0.f;
          C[(size_t)m * D_ + n] = (unsigned short)f2bf(v);
        }
      }
    }
  }
}

// ---- K1: X = bf16(emb[src]+pos) (512 blks, 8 rows) + WET transpose + ENC zero ----
__global__ void prep1(const int* __restrict__ src, const float* __restrict__ emb,
                      const float* __restrict__ pos, const float* __restrict__ Wenc,
                      unsigned short* __restrict__ X, unsigned short* __restrict__ WET,
                      unsigned short* __restrict__ ENC) {
  __shared__ float sh[64 * 65];
  int bid = blockIdx.x, tid = threadIdx.x;
  if (bid < 512) {
    int lane = tid & 63, w = tid >> 6;
    for (int u = 0; u < 2; ++u) {
      int row = bid * 8 + u * 4 + w;
      int s = src[row];
      int l = row & (L_ - 1);
      int d = lane * 8;
      const float4* ep = (const float4*)(emb + (size_t)s * D_ + d);
      const float4* pp = (const float4*)(pos + (size_t)l * D_ + d);
      float4 a0 = ep[0], a1 = ep[1];
      float4 b0 = pp[0], b1 = pp[1];
      uint4 o;
      o.x = f2bf(a0.x + b0.x) | (f2bf(a0.y + b0.y) << 16);
      o.y = f2bf(a0.z + b0.z) | (f2bf(a0.w + b0.w) << 16);
      o.z = f2bf(a1.x + b1.x) | (f2bf(a1.y + b1.y) << 16);
      o.w = f2bf(a1.z + b1.z) | (f2bf(a1.w + b1.w) << 16);
      *(uint4*)(X + (size_t)row * D_ + d) = o;
    }
  } else if (bid < 576) {
    transw_dev(Wenc, WET, 512, bid - 512, sh);
  } else {
    if (tid < 64) {
      uint4 z = {0u, 0u, 0u, 0u};
      *(uint4*)(ENC + (size_t)R_ * D_ + (tid & 63) * 8) = z;
    }
  }
}

// ---- K2: encoder GEMM (512 blks) + WDT/WGT/TOK prep tails ----
__global__ __launch_bounds__(256, 2) void gemm_enc(
    const unsigned short* __restrict__ X, const unsigned short* __restrict__ WET,
    const float* __restrict__ benc, unsigned short* __restrict__ ENC,
    const float* __restrict__ Wdec, const float* __restrict__ Wgen,
    const int* __restrict__ dur,
    unsigned short* __restrict__ WDT, unsigned short* __restrict__ WGT,
    int* __restrict__ TOK) {
  __shared__ __align__(16) char smem[65536];
  int bid = blockIdx.x;
  if (bid < 512) {
    // n-tile in lsb: each B-panel (the 64x-reused operand) stays XCD-local
    gemm_tile(X, WET, benc, ENC, (bid >> 3) * 64, (bid & 7) * 64, R_ - 1, R_, smem);
  } else if (bid < 576) {
    transw_dev(Wdec, WDT, 512, bid - 512, (float*)smem);
  } else if (bid < 592) {
    transw_dev(Wgen, WGT, MELS_, bid - 576, (float*)smem);
  } else {
    tok_dev(dur, TOK, bid - 592, (int*)smem);
  }
}

// ---- K3: decoder GEMM (520 blks) + duration head (256 tail blks) ----
__global__ __launch_bounds__(256, 2) void gemm_dec(
    const unsigned short* __restrict__ ENC, const unsigned short* __restrict__ WDT,
    const float* __restrict__ bdec, unsigned short* __restrict__ DEC,
    const float* __restrict__ wdur, const float* __restrict__ bdur,
    float* __restrict__ durout) {
  __shared__ __align__(16) char smem[65536];
  int bid = blockIdx.x, tid = threadIdx.x;
  int lane = tid & 63, w = tid >> 6;
  if (bid >= 520) {                                   // duration head: 16 rows/block
    int b2 = bid - 520;
    float4 w0 = *(const float4*)(wdur + lane * 8);
    float4 w1 = *(const float4*)(wdur + lane * 8 + 4);
    float bv = bdur[0];
    for (int rep = 0; rep < 4; ++rep) {
      int row = b2 * 16 + w * 4 + rep;
      const uint4 e = *(const uint4*)(ENC + (size_t)row * D_ + lane * 8);
      float s = 0.f;
      s += bf2f(e.x & 0xffffu) * w0.x;  s += bf2f(e.x >> 16) * w0.y;
      s += bf2f(e.y & 0xffffu) * w0.z;  s += bf2f(e.y >> 16) * w0.w;
      s += bf2f(e.z & 0xffffu) * w1.x;  s += bf2f(e.z >> 16) * w1.y;
      s += bf2f(e.w & 0xffffu) * w1.z;  s += bf2f(e.w >> 16) * w1.w;
      for (int off = 32; off > 0; off >>= 1) s += __shfl_down(s, off, 64);
      if (lane == 0) durout[row] = s + bv;
    }
    return;
  }
  gemm_tile(ENC, WDT, bdec, DEC, (bid >> 3) * 64, (bid & 7) * 64, R_, R_ + 1, smem);
}

// ---- K4: mel^T[m][r] = dec[r]·W_gen[:,m] + b_gen[m] ; K split over 4 waves ----
__global__ void genk(const unsigned short* __restrict__ dec, const unsigned short* __restrict__ wgT,
                     const float* __restrict__ bgen, float* __restrict__ melT) {
  __shared__ float sh[4 * 80 * 16];
  int tid = threadIdx.x;
  int lane = tid & 63, w = tid >> 6;
  int col = lane & 15, quad = lane >> 4;
  int n0 = blockIdx.x * 16;
  int n = n0 + col;
  int nc = min(n, R_);
  f32x4 acc[5] = {};
  const unsigned short* dp = dec + (size_t)nc * D_ + quad * 8;
  for (int ks = 0; ks < 4; ++ks) {
    int k0 = (w * 4 + ks) * 32;
    bf16x8 bfr = *(const bf16x8*)(dp + k0);
    for (int mt = 0; mt < 5; ++mt) {
      bf16x8 afr = *(const bf16x8*)(wgT + (size_t)(mt * 16 + col) * D_ + k0 + quad * 8);
      acc[mt] = __builtin_amdgcn_mfma_f32_16x16x32_bf16(afr, bfr, acc[mt], 0, 0, 0);
    }
  }
  for (int mt = 0; mt < 5; ++mt)
    for (int i = 0; i < 4; ++i)
      sh[w * 1280 + (mt * 16 + quad * 4 + i) * 16 + col] = acc[mt][i];
  __syncthreads();
  for (int j = 0; j < 5; ++j) {
    int idx = j * 256 + tid;
    float v = sh[idx] + sh[1280 + idx] + sh[2560 + idx] + sh[3840 + idx];
    int m = idx >> 4;
    int nn = n0 + (idx & 15);
    if (nn <= R_) melT[(size_t)m * CS_ + nn] = v + bgen[m];
  }
}

// ---- K5: out[b][m][t] = mel^T[m][tok[b][t]] ; float4 coalesced stores ----
__global__ void outk(const int* __restrict__ TOK, const float* __restrict__ melT,
                     float* __restrict__ out) {
  int b = blockIdx.y;
  int tl = blockIdx.x * 128 + (threadIdx.x & 31) * 4;
  int m0 = threadIdx.x >> 5;
  int4 tg = *(const int4*)(TOK + b * T_ + tl);
  float* ob = out + (size_t)b * MELS_ * T_ + tl;
  for (int it = 0; it < 10; ++it) {
    int m = m0 + it * 8;
    const float* mr = melT + (size_t)m * CS_;
    float4 v = make_float4(mr[tg.x], mr[tg.y], mr[tg.z], mr[tg.w]);
    *(float4*)(ob + (size_t)m * T_) = v;
  }
}

extern "C" void kernel_launch(void* const* d_in, const int* in_sizes, int n_in,
                              void* d_out, int out_size, void* d_ws, size_t ws_size,
                              hipStream_t stream) {
  const int* src = (const int*)d_in[0];
  const int* dur = (const int*)d_in[1];
  const float* emb = (const float*)d_in[3];
  const float* pos = (const float*)d_in[4];
  const float* Wenc = (const float*)d_in[5];
  const float* benc = (const float*)d_in[6];
  const float* Wdur = (const float*)d_in[7];
  const float* bdur = (const float*)d_in[8];
  const float* Wdec = (const float*)d_in[9];
  const float* bdec = (const float*)d_in[10];
  const float* Wgen = (const float*)d_in[11];
  const float* bgen = (const float*)d_in[12];

  char* ws = (char*)d_ws;
  unsigned short* X   = (unsigned short*)(ws + 0);          // 4096x512 bf16
  unsigned short* ENC = (unsigned short*)(ws + 4194304);    // 4097x512 bf16 (row 4096 = 0)
  unsigned short* DEC = (unsigned short*)(ws + 8389632);    // 4097x512 bf16
  unsigned short* WET = (unsigned short*)(ws + 12584960);   // W_enc^T 512x512 bf16
  unsigned short* WDT = (unsigned short*)(ws + 13109248);   // W_dec^T 512x512 bf16
  unsigned short* WGT = (unsigned short*)(ws + 13633536);   // W_gen^T 80x512 bf16
  int* TOK            = (int*)(ws + 13715456);              // 16x3072 int
  float* MELT         = (float*)(ws + 13912064);            // 80x4104 f32

  float* out = (float*)d_out;
  float* durout = out + (size_t)B_ * MELS_ * T_;            // 3,932,160

  prep1<<<577, 256, 0, stream>>>(src, emb, pos, Wenc, X, WET, ENC);
  gemm_enc<<<608, 256, 0, stream>>>(X, WET, benc, ENC, Wdec, Wgen, dur, WDT, WGT, TOK);
  gemm_dec<<<776, 256, 0, stream>>>(ENC, WDT, bdec, DEC, Wdur, bdur, durout);
  genk<<<257, 256, 0, stream>>>(DEC, WGT, bgen, MELT);
  outk<<<dim3(24, 16), 256, 0, stream>>>(TOK, MELT, out);
}

// Round 6
// 122.250 us; speedup vs baseline: 5.3843x; 1.0524x over previous
//
#include <hip/hip_runtime.h>

#define D_ 512
#define L_ 256
#define B_ 16
#define T_ 3072
#define MELS_ 80
#define R_ 4096          // B_*L_ unique token rows
#define CS_ 4104         // mel^T column stride (floats)

typedef __bf16 bf16x8 __attribute__((ext_vector_type(8)));
typedef float f32x4 __attribute__((ext_vector_type(4)));

__device__ __forceinline__ unsigned f2bf(float f) {
  union { float f; unsigned u; } x; x.f = f;
  return (x.u + 0x7FFFu + ((x.u >> 16) & 1u)) >> 16;   // RNE
}
__device__ __forceinline__ float bf2f(unsigned h) {
  union { unsigned u; float f; } x; x.u = h << 16;
  return x.f;
}

// dst[n][k] = bf16(src[k][n]) ; src is [512][N] f32, dst is [N][512] bf16
__device__ __forceinline__ void transw_dev(const float* __restrict__ src,
                                           unsigned short* __restrict__ dst,
                                           int N, int local, float* sh) {
  int kt = local & 7, nt = local >> 3;
  int k0 = kt * 64, n0 = nt * 64;
  int tid = threadIdx.x;
  int c = tid & 63, r4 = tid >> 6;
  for (int it = 0; it < 16; ++it) {
    int r = it * 4 + r4;
    int n = n0 + c;
    sh[r * 65 + c] = (n < N) ? src[(k0 + r) * N + n] : 0.f;
  }
  __syncthreads();
  for (int it = 0; it < 16; ++it) {
    int r = it * 4 + r4;
    int n = n0 + r;
    if (n < N) dst[n * D_ + k0 + c] = (unsigned short)f2bf(sh[c * 65 + r]);
  }
}

// cumsum(dur) + searchsorted(right) -> enc-row index per frame (R_ = invalid)
__device__ __forceinline__ void tok_dev(const int* __restrict__ dur,
                                        int* __restrict__ TOK, int b, int* cs) {
  int tid = threadIdx.x;
  cs[tid] = dur[b * L_ + tid];
  for (int off = 1; off < L_; off <<= 1) {
    __syncthreads();
    int v = (tid >= off) ? cs[tid - off] : 0;
    __syncthreads();
    cs[tid] += v;
  }
  __syncthreads();
  for (int t = tid; t < T_; t += 256) {
    int lo = 0, hi = L_;
    while (lo < hi) { int mid = (lo + hi) >> 1; if (cs[mid] <= t) lo = mid + 1; else hi = mid; }
    TOK[b * T_ + t] = (lo < L_) ? (b * L_ + lo) : R_;
  }
}

// ---- C = relu(A @ Bt^T + bias); 64x64 tile, BK=128 (4 barrier-drains) ----
__device__ __forceinline__ void gemm_tile(
    const unsigned short* __restrict__ A, const unsigned short* __restrict__ Bt,
    const float* __restrict__ bias, unsigned short* __restrict__ C,
    int m0, int n0, int mclamp, int mstore, short* lsA, short* lsB) {
  int tid = threadIdx.x;
  int lane = tid & 63, w = tid >> 6;
  int wm = w >> 1, wn = w & 1;
  int col = lane & 15, quad = lane >> 4;
  f32x4 acc[2][2] = {};
  for (int ks = 0; ks < 4; ++ks) {
    int k0 = ks * 128;
    __syncthreads();                                  // LDS reuse guard
    for (int it = 0; it < 4; ++it) {
      int linear = it * 256 + tid;
      int row = linear >> 4, p = linear & 15;
      int seg = (p + row) & 15;                       // additive swizzle
      const unsigned short* ga = A + (size_t)min(m0 + row, mclamp) * D_ + k0 + seg * 8;
      const unsigned short* gb = Bt + (size_t)(n0 + row) * D_ + k0 + seg * 8;
      short* la = lsA + (size_t)(it * 256 + (tid & ~63)) * 8;  // wave-uniform base
      short* lb = lsB + (size_t)(it * 256 + (tid & ~63)) * 8;
      __builtin_amdgcn_global_load_lds((const __attribute__((address_space(1))) void*)ga,
                                       (__attribute__((address_space(3))) void*)la, 16, 0, 0);
      __builtin_amdgcn_global_load_lds((const __attribute__((address_space(1))) void*)gb,
                                       (__attribute__((address_space(3))) void*)lb, 16, 0, 0);
    }
    __syncthreads();                                  // drains vmcnt(0)
    for (int kk = 0; kk < 4; ++kk) {
      int s = kk * 4 + quad;                          // chunk 0..15 within BK
      bf16x8 af[2], bfr[2];
      for (int mt = 0; mt < 2; ++mt) {
        int r = wm * 32 + mt * 16 + col;
        af[mt] = *(const bf16x8*)(lsA + (size_t)r * 128 + ((s - r) & 15) * 8);
      }
      for (int nt = 0; nt < 2; ++nt) {
        int r = wn * 32 + nt * 16 + col;
        bfr[nt] = *(const bf16x8*)(lsB + (size_t)r * 128 + ((s - r) & 15) * 8);
      }
      for (int mt = 0; mt < 2; ++mt)
        for (int nt = 0; nt < 2; ++nt)
          acc[mt][nt] = __builtin_amdgcn_mfma_f32_16x16x32_bf16(af[mt], bfr[nt], acc[mt][nt], 0, 0, 0);
    }
  }
  for (int nt = 0; nt < 2; ++nt) {
    int n = n0 + wn * 32 + nt * 16 + col;
    float bn = bias[n];
    for (int mt = 0; mt < 2; ++mt) {
      int mb = m0 + wm * 32 + mt * 16 + quad * 4;
      for (int i = 0; i < 4; ++i) {
        int m = mb + i;
        if (m < mstore) {
          float v = acc[mt][nt][i] + bn;
          v = v > 0.f ? v : 0.f;
          C[(size_t)m * D_ + n] = (unsigned short)f2bf(v);
        }
      }
    }
  }
}

// ---- L1: X = bf16(emb[src]+pos) (512 blks, 8 rows) + WET transpose + ENC zero ----
__global__ void prep1(const int* __restrict__ src, const float* __restrict__ emb,
                      const float* __restrict__ pos, const float* __restrict__ Wenc,
                      unsigned short* __restrict__ X, unsigned short* __restrict__ WET,
                      unsigned short* __restrict__ ENC) {
  __shared__ float sh[64 * 65];
  int bid = blockIdx.x, tid = threadIdx.x;
  if (bid < 512) {
    int lane = tid & 63, w = tid >> 6;
    for (int u = 0; u < 2; ++u) {
      int row = bid * 8 + u * 4 + w;
      int s = src[row];
      int l = row & (L_ - 1);
      int d = lane * 8;
      const float4* ep = (const float4*)(emb + (size_t)s * D_ + d);
      const float4* pp = (const float4*)(pos + (size_t)l * D_ + d);
      float4 a0 = ep[0], a1 = ep[1];
      float4 b0 = pp[0], b1 = pp[1];
      uint4 o;
      o.x = f2bf(a0.x + b0.x) | (f2bf(a0.y + b0.y) << 16);
      o.y = f2bf(a0.z + b0.z) | (f2bf(a0.w + b0.w) << 16);
      o.z = f2bf(a1.x + b1.x) | (f2bf(a1.y + b1.y) << 16);
      o.w = f2bf(a1.z + b1.z) | (f2bf(a1.w + b1.w) << 16);
      *(uint4*)(X + (size_t)row * D_ + d) = o;
    }
  } else if (bid < 576) {
    transw_dev(Wenc, WET, 512, bid - 512, sh);
  } else {
    if (tid < 64) {
      uint4 z = {0u, 0u, 0u, 0u};
      *(uint4*)(ENC + (size_t)R_ * D_ + (tid & 63) * 8) = z;
    }
  }
}

// ---- L2: encoder GEMM (512 blks) + WDT/WGT/TOK prep tails ----
__global__ __launch_bounds__(256, 4) void gemm_enc(
    const unsigned short* __restrict__ X, const unsigned short* __restrict__ WET,
    const float* __restrict__ benc, unsigned short* __restrict__ ENC,
    const float* __restrict__ Wdec, const float* __restrict__ Wgen,
    const int* __restrict__ dur,
    unsigned short* __restrict__ WDT, unsigned short* __restrict__ WGT,
    int* __restrict__ TOK) {
  __shared__ __align__(16) char smem[32768];
  int bid = blockIdx.x;
  if (bid < 512) {
    // n-tile in lsb: each B-panel (the 64x-reused operand) stays XCD-local
    gemm_tile(X, WET, benc, ENC, (bid >> 3) * 64, (bid & 7) * 64, R_ - 1, R_,
              (short*)smem, (short*)(smem + 16384));
  } else if (bid < 576) {
    transw_dev(Wdec, WDT, 512, bid - 512, (float*)smem);
  } else if (bid < 592) {
    transw_dev(Wgen, WGT, MELS_, bid - 576, (float*)smem);
  } else {
    tok_dev(dur, TOK, bid - 592, (int*)smem);
  }
}

// ---- L3: decoder GEMM (520 blks) + duration head (256 tail blks) ----
__global__ __launch_bounds__(256, 4) void gemm_dec(
    const unsigned short* __restrict__ ENC, const unsigned short* __restrict__ WDT,
    const float* __restrict__ bdec, unsigned short* __restrict__ DEC,
    const float* __restrict__ wdur, const float* __restrict__ bdur,
    float* __restrict__ durout) {
  __shared__ __align__(16) char smem[32768];
  int bid = blockIdx.x, tid = threadIdx.x;
  int lane = tid & 63, w = tid >> 6;
  if (bid >= 520) {                                   // duration head: 16 rows/block
    int b2 = bid - 520;
    float4 w0 = *(const float4*)(wdur + lane * 8);
    float4 w1 = *(const float4*)(wdur + lane * 8 + 4);
    float bv = bdur[0];
    for (int rep = 0; rep < 4; ++rep) {
      int row = b2 * 16 + w * 4 + rep;
      const uint4 e = *(const uint4*)(ENC + (size_t)row * D_ + lane * 8);
      float s = 0.f;
      s += bf2f(e.x & 0xffffu) * w0.x;  s += bf2f(e.x >> 16) * w0.y;
      s += bf2f(e.y & 0xffffu) * w0.z;  s += bf2f(e.y >> 16) * w0.w;
      s += bf2f(e.z & 0xffffu) * w1.x;  s += bf2f(e.z >> 16) * w1.y;
      s += bf2f(e.w & 0xffffu) * w1.z;  s += bf2f(e.w >> 16) * w1.w;
      for (int off = 32; off > 0; off >>= 1) s += __shfl_down(s, off, 64);
      if (lane == 0) durout[row] = s + bv;
    }
    return;
  }
  gemm_tile(ENC, WDT, bdec, DEC, (bid >> 3) * 64, (bid & 7) * 64, R_, R_ + 1,
            (short*)smem, (short*)(smem + 16384));
}

// ---- L4: mel^T[m][r] = dec[r]·W_gen[:,m] + b_gen[m] ; K split over 4 waves ----
__global__ void genk(const unsigned short* __restrict__ dec, const unsigned short* __restrict__ wgT,
                     const float* __restrict__ bgen, float* __restrict__ melT) {
  __shared__ float sh[4 * 80 * 16];
  int tid = threadIdx.x;
  int lane = tid & 63, w = tid >> 6;
  int col = lane & 15, quad = lane >> 4;
  int n0 = blockIdx.x * 16;
  int n = n0 + col;
  int nc = min(n, R_);
  f32x4 acc[5] = {};
  const unsigned short* dp = dec + (size_t)nc * D_ + quad * 8;
  for (int ks = 0; ks < 4; ++ks) {
    int k0 = (w * 4 + ks) * 32;
    bf16x8 bfr = *(const bf16x8*)(dp + k0);
    for (int mt = 0; mt < 5; ++mt) {
      bf16x8 afr = *(const bf16x8*)(wgT + (size_t)(mt * 16 + col) * D_ + k0 + quad * 8);
      acc[mt] = __builtin_amdgcn_mfma_f32_16x16x32_bf16(afr, bfr, acc[mt], 0, 0, 0);
    }
  }
  for (int mt = 0; mt < 5; ++mt)
    for (int i = 0; i < 4; ++i)
      sh[w * 1280 + (mt * 16 + quad * 4 + i) * 16 + col] = acc[mt][i];
  __syncthreads();
  for (int j = 0; j < 5; ++j) {
    int idx = j * 256 + tid;
    float v = sh[idx] + sh[1280 + idx] + sh[2560 + idx] + sh[3840 + idx];
    int m = idx >> 4;
    int nn = n0 + (idx & 15);
    if (nn <= R_) melT[(size_t)m * CS_ + nn] = v + bgen[m];
  }
}

// ---- L5: out[b][m][t] = mel^T[m][tok[b][t]] ; float4 coalesced stores ----
__global__ void outk(const int* __restrict__ TOK, const float* __restrict__ melT,
                     float* __restrict__ out) {
  int b = blockIdx.y;
  int tl = blockIdx.x * 128 + (threadIdx.x & 31) * 4;
  int m0 = threadIdx.x >> 5;
  int4 tg = *(const int4*)(TOK + b * T_ + tl);
  float* ob = out + (size_t)b * MELS_ * T_ + tl;
  for (int it = 0; it < 10; ++it) {
    int m = m0 + it * 8;
    const float* mr = melT + (size_t)m * CS_;
    float4 v = make_float4(mr[tg.x], mr[tg.y], mr[tg.z], mr[tg.w]);
    *(float4*)(ob + (size_t)m * T_) = v;
  }
}

extern "C" void kernel_launch(void* const* d_in, const int* in_sizes, int n_in,
                              void* d_out, int out_size, void* d_ws, size_t ws_size,
                              hipStream_t stream) {
  const int* src = (const int*)d_in[0];
  const int* dur = (const int*)d_in[1];
  const float* emb = (const float*)d_in[3];
  const float* pos = (const float*)d_in[4];
  const float* Wenc = (const float*)d_in[5];
  const float* benc = (const float*)d_in[6];
  const float* Wdur = (const float*)d_in[7];
  const float* bdur = (const float*)d_in[8];
  const float* Wdec = (const float*)d_in[9];
  const float* bdec = (const float*)d_in[10];
  const float* Wgen = (const float*)d_in[11];
  const float* bgen = (const float*)d_in[12];

  char* ws = (char*)d_ws;
  unsigned short* X   = (unsigned short*)(ws + 0);          // 4096x512 bf16
  unsigned short* ENC = (unsigned short*)(ws + 4194304);    // 4097x512 bf16 (row 4096 = 0)
  unsigned short* DEC = (unsigned short*)(ws + 8389632);    // 4097x512 bf16
  unsigned short* WET = (unsigned short*)(ws + 12584960);   // W_enc^T 512x512 bf16
  unsigned short* WDT = (unsigned short*)(ws + 13109248);   // W_dec^T 512x512 bf16
  unsigned short* WGT = (unsigned short*)(ws + 13633536);   // W_gen^T 80x512 bf16
  int* TOK            = (int*)(ws + 13715456);              // 16x3072 int
  float* MELT         = (float*)(ws + 13912064);            // 80x4104 f32

  float* out = (float*)d_out;
  float* durout = out + (size_t)B_ * MELS_ * T_;            // 3,932,160

  prep1<<<577, 256, 0, stream>>>(src, emb, pos, Wenc, X, WET, ENC);
  gemm_enc<<<608, 256, 0, stream>>>(X, WET, benc, ENC, Wdec, Wgen, dur, WDT, WGT, TOK);
  gemm_dec<<<776, 256, 0, stream>>>(ENC, WDT, bdec, DEC, Wdur, bdur, durout);
  genk<<<257, 256, 0, stream>>>(DEC, WGT, bgen, MELT);
  outk<<<dim3(24, 16), 256, 0, stream>>>(TOK, MELT, out);
}